// Round 10
// baseline (291.985 us; speedup 1.0000x reference)
//
#include <hip/hip_runtime.h>

// CandidateScorer on MI355X (gfx950).
//
// Math (exact rewrite of the reference):
//   gp-part of combined is candidate-independent      -> folded into bias b1'
//   go/to gathers take only 361 distinct values each  -> precomputed tables
//   h1[n,j] = relu(T_go[go[n],j] + T_to[to[n],j] + (cand @ W1c)[n,j] + b1'[j])
//   scores  = relu(h1 @ W2 + b2) @ W3 + b3   (GEMM3 fused into GEMM2 epilogue)
//
// R1: XCD swizzle. R3: BK=64 + XOR LDS swizzle (conflicts 0, ~1012 TF).
// R4: Ttab bf16. R5: parallel pool fix. R7/R8: dbuf regressions -> gemm2
//     FROZEN at BK=64 single-buffer (m97-family plateau).
// R9: ttab unroll was slightly negative -> reverted to R6 prep.
// R10: gemm1 epilogue diet — go/to index loads issued before first barrier
//      (hide 200cyc under staging+MFMA), phase2+3 merged (direct 32B-segment
//      h1 stores; the 4 ni-segments/row share one 128B line -> L2 combines).
//      Saves 1 barrier + 8 ds_read_b128 + LDS restage per block.

using bf16x8 = __attribute__((ext_vector_type(8))) __bf16;
using f32x4  = __attribute__((ext_vector_type(4))) float;
using i32x4  = __attribute__((ext_vector_type(4))) int;

__device__ __forceinline__ unsigned short f2bf(float f) {
  unsigned int u = __float_as_uint(f);
  u += 0x7fffu + ((u >> 16) & 1u);          // round-to-nearest-even
  return (unsigned short)(u >> 16);
}
__device__ __forceinline__ float bf2f(unsigned int s) {
  return __uint_as_float(s << 16);
}

// Async global->LDS, 16B per lane. LDS dest is wave-uniform base + lane*16.
__device__ __forceinline__ void async_copy16(const void* g, void* l) {
  __builtin_amdgcn_global_load_lds(
      (__attribute__((address_space(1))) void*)(unsigned long long)g,
      (__attribute__((address_space(3))) void*)(unsigned int)(unsigned long long)l,
      16, 0, 0);
}

// ---------------------------------------------------------------- pool
// 64 blocks x 256 threads: wave w reduces channel bx*4+w (fully parallel).
// Blocks 0-3 additionally init b1p = b1 (atomic target for prep's b1p range).
__global__ void pool_kernel(const float* __restrict__ pfm, float* __restrict__ gp,
                            const float* __restrict__ b1, float* __restrict__ b1p) {
  int t = threadIdx.x, bx = blockIdx.x;
  int wave = t >> 6, lane = t & 63;
  int c = bx * 4 + wave;
  float s = 0.f;
  for (int i = lane; i < 361; i += 64) s += pfm[c * 361 + i];
#pragma unroll
  for (int off = 32; off > 0; off >>= 1) s += __shfl_down(s, off, 64);
  if (lane == 0) gp[c] = s * (1.0f / 361.0f);
  if (bx < 4) b1p[bx * 256 + t] = b1[bx * 256 + t];
}

// ---------------------------------------------------------------- fused prep
// Block ranges (long pole first):
//   [0,368)      Ttab (bf16): T[s][pos][j] = sum_c pfm[c][pos]*W1[s*256+c][j]
//   [368,496)    b1p[j] += sum over 8 channels of gp[c]*W1[512+c][j] (atomic)
//   [496,752)    w2T[n][k] = bf16(W2[k][n])  (64x64 LDS-tiled transpose)
//   [752,1008)   go/to decode
//   [1008,1264)  scores = b3
//   [1264,1520)  w1cT[n][k] = bf16(W1[768+k][n])
__global__ void prep_kernel(const float* __restrict__ pfm, const float* __restrict__ cand,
                            const float* __restrict__ W1, const float* __restrict__ gp,
                            const float* __restrict__ W2, const float* __restrict__ b3,
                            int* __restrict__ go_off, int* __restrict__ to_off,
                            float* __restrict__ scores,
                            unsigned short* __restrict__ w1cT,
                            unsigned short* __restrict__ w2T,
                            unsigned short* __restrict__ Tb,
                            float* __restrict__ b1p) {
  __shared__ __align__(16) char smem[16640];
  int bx = blockIdx.x, t = threadIdx.x;

  if (bx < 368) {
    int b = bx;                      // 2 * 46 * 4 = 368 blocks
    int s = b / 184;
    int rem = b % 184;
    int p8 = rem >> 2;
    int jc = rem & 3;
    int j = jc * 256 + t;
    float (*pf)[256] = (float(*)[256])smem;   // [8][256] = 8KB
#pragma unroll
    for (int i = 0; i < 8; i++) {
      int p = p8 * 8 + i;
      pf[i][t] = (p < 361) ? pfm[t * 361 + p] : 0.f;   // t = channel
    }
    __syncthreads();
    float acc[8] = {0.f, 0.f, 0.f, 0.f, 0.f, 0.f, 0.f, 0.f};
    for (int c = 0; c < 256; c++) {
      float w = W1[(size_t)(s * 256 + c) * 1024 + j];
#pragma unroll
      for (int i = 0; i < 8; i++) acc[i] += pf[i][c] * w;
    }
#pragma unroll
    for (int i = 0; i < 8; i++) {
      int p = p8 * 8 + i;
      if (p < 361) Tb[((size_t)s * 361 + p) * 1024 + j] = f2bf(acc[i]);
    }
  } else if (bx < 496) {
    int b = bx - 368;                // 128 blocks: (jc 0..3) x (cchunk 0..31)
    int j = (b & 3) * 256 + t;
    int c0 = (b >> 2) * 8;
    float acc = 0.f;
#pragma unroll
    for (int i = 0; i < 8; i++)
      acc += gp[c0 + i] * W1[(size_t)(512 + c0 + i) * 1024 + j];
    atomicAdd(&b1p[j], acc);
  } else if (bx < 752) {
    int b = bx - 496;                // 256 tiles (16 x 16)
    float (*Ts)[65] = (float(*)[65])smem;     // [64][65] = 16640 B
    int kt = b >> 4, nt = b & 15;
#pragma unroll
    for (int i = 0; i < 4; i++) {
      int c = i * 256 + t;           // 1024 f32x4 chunks
      int r = c >> 4, ch = c & 15;
      f32x4 v = *(const f32x4*)&W2[(size_t)(kt * 64 + r) * 1024 + nt * 64 + ch * 4];
      Ts[r][ch * 4 + 0] = v[0]; Ts[r][ch * 4 + 1] = v[1];
      Ts[r][ch * 4 + 2] = v[2]; Ts[r][ch * 4 + 3] = v[3];
    }
    __syncthreads();
#pragma unroll
    for (int i = 0; i < 2; i++) {
      int c = i * 256 + t;           // 512 out-chunks of 8 bf16
      int n = c >> 3, ch = c & 7;
      unsigned short pack[8];
#pragma unroll
      for (int j = 0; j < 8; j++) pack[j] = f2bf(Ts[ch * 8 + j][n]);
      *(i32x4*)&w2T[(size_t)(nt * 64 + n) * 1024 + kt * 64 + ch * 8] = *(i32x4*)pack;
    }
  } else if (bx < 1008) {
    int n = (bx - 752) * 256 + t;
    const float* cf = cand + (size_t)n * 64;
    int gr = min(max((int)(cf[5] * 18.0f), 0), 18);
    int gc = min(max((int)(cf[6] * 18.0f), 0), 18);
    int tr = min(max((int)(cf[7] * 18.0f), 0), 18);
    int tc = min(max((int)(cf[8] * 18.0f), 0), 18);
    go_off[n] = gr * 19 + gc;
    to_off[n] = tr * 19 + tc;
  } else if (bx < 1264) {
    scores[(bx - 1008) * 256 + t] = b3[0];
  } else {
    int o = (bx - 1264) * 256 + t;   // < 65536
    int n = o >> 6, k = o & 63;
    w1cT[o] = f2bf(W1[(size_t)(768 + k) * 1024 + n]);
  }
}

// ---------------------------------------------------------------- GEMM1 (fused)

// h1(65536 x 1024) = relu(cand(f32) @ W1c + T_go[go] + T_to[to] + b1p)
// 128x128 tile, K=64 single step. A staged via f32 load + convert + ds_write;
// B via async_copy16. LDS XOR-swizzled (chunk (row,s) holds kchunk s^(row&7)).
// R10 epilogue: go/to indices loaded before barrier 1; phase2 stores direct.
__launch_bounds__(256, 2)
__global__ void gemm1_kernel(const float* __restrict__ cand,
                             const unsigned short* __restrict__ w1cT,
                             unsigned short* __restrict__ h1out,
                             const unsigned short* __restrict__ Tb,
                             const int* __restrict__ go_off,
                             const int* __restrict__ to_off,
                             const float* __restrict__ bias) {
  __shared__ __align__(16) char smem[34816];           // max(32K stage, 34K Cs)
  unsigned short* As = (unsigned short*)smem;          // [128][64] 16KB
  unsigned short* Bs = (unsigned short*)(smem + 16384);// [128][64] 16KB
  unsigned short* Cs = (unsigned short*)smem;          // [128][136] bf16 (aliased)

  const int tid  = threadIdx.x;
  const int lane = tid & 63;
  const int wave = tid >> 6;
  const int wm   = wave & 1;
  const int wn   = wave >> 1;
  const int quad = lane >> 4;
  const int r16  = lane & 15;

  const int bx    = blockIdx.x;
  const int xcd   = bx & 7;
  const int seq   = bx >> 3;
  const int ntile = seq & 7;
  const int mtile = ((seq >> 3) << 3) | xcd;
  const long rowbase = (long)mtile * 128;
  const int  colbase = ntile * 128;

  // ---- stage A: load f32, convert, ds_write (4 chunks of 16B per thread)
#pragma unroll
  for (int i = 0; i < 4; i++) {
    int c = i * 256 + tid;                 // physical chunk
    int row = c >> 3, s = c & 7;
    int kc = s ^ (row & 7);                // logical k-chunk
    const float* src = cand + (rowbase + row) * 64 + kc * 8;
    f32x4 v0 = *(const f32x4*)src;
    f32x4 v1 = *(const f32x4*)(src + 4);
    unsigned int p[4];
    p[0] = f2bf(v0[0]) | ((unsigned int)f2bf(v0[1]) << 16);
    p[1] = f2bf(v0[2]) | ((unsigned int)f2bf(v0[3]) << 16);
    p[2] = f2bf(v1[0]) | ((unsigned int)f2bf(v1[1]) << 16);
    p[3] = f2bf(v1[2]) | ((unsigned int)f2bf(v1[3]) << 16);
    *(i32x4*)&As[c * 8] = *(i32x4*)p;
  }
  // ---- stage B: async copy w1cT tile (4 chunks per thread)
#pragma unroll
  for (int i = 0; i < 4; i++) {
    int c = i * 256 + tid;
    int row = c >> 3, s = c & 7;
    int kc = s ^ (row & 7);
    async_copy16(w1cT + (colbase + row) * 64 + kc * 8, &Bs[c * 8]);
  }
  // ---- early-issue go/to index loads for the epilogue gathers (R10):
  // first level of the dependent index->gather chain hides under MFMA.
  int goi[8], toi[8];
#pragma unroll
  for (int i = 0; i < 8; i++) {
    int r = (i * 256 + tid) >> 4;
    goi[i] = go_off[rowbase + r];
    toi[i] = to_off[rowbase + r];
  }
  __syncthreads();

  const f32x4 zero4 = {0.f, 0.f, 0.f, 0.f};
  f32x4 acc[4][4];
#pragma unroll
  for (int i = 0; i < 4; i++)
#pragma unroll
    for (int j = 0; j < 4; j++) acc[i][j] = zero4;

#pragma unroll
  for (int ks = 0; ks < 2; ks++) {
    bf16x8 af[4], bfv[4];
#pragma unroll
    for (int mi = 0; mi < 4; mi++) {
      int r = wm * 64 + mi * 16 + r16;
      int phys = (ks * 4 + quad) ^ (r16 & 7);
      af[mi] = *(const bf16x8*)&As[r * 64 + phys * 8];
    }
#pragma unroll
    for (int ni = 0; ni < 4; ni++) {
      int r = wn * 64 + ni * 16 + r16;
      int phys = (ks * 4 + quad) ^ (r16 & 7);
      bfv[ni] = *(const bf16x8*)&Bs[r * 64 + phys * 8];
    }
#pragma unroll
    for (int mi = 0; mi < 4; mi++)
#pragma unroll
      for (int ni = 0; ni < 4; ni++)
        acc[mi][ni] = __builtin_amdgcn_mfma_f32_16x16x32_bf16(af[mi], bfv[ni],
                                                              acc[mi][ni], 0, 0, 0);
  }
  __syncthreads();   // staging LDS dead; Cs takes over

  // Phase 1: Cs[r][c] = bf16(T_go[go[r]][c] + T_to[to[r]][c] + bias[c]).
#pragma unroll
  for (int i = 0; i < 8; i++) {
    int c = i * 256 + tid;                    // 2048 chunks of 8 cols
    int r = c >> 4, ch = c & 15;
    const unsigned short* tg = Tb + (long)goi[i] * 1024 + colbase + ch * 8;
    const unsigned short* tt = Tb + 361L * 1024 + (long)toi[i] * 1024 + colbase + ch * 8;
    i32x4 ga = *(const i32x4*)tg;
    i32x4 gb = *(const i32x4*)tt;
    const float* bp = bias + colbase + ch * 8;
    f32x4 b0 = *(const f32x4*)bp;
    f32x4 b1v = *(const f32x4*)(bp + 4);
    unsigned int p[4];
#pragma unroll
    for (int w = 0; w < 4; w++) {
      unsigned int ua = (unsigned int)ga[w], ub = (unsigned int)gb[w];
      float lo = bf2f(ua & 0xffffu) + bf2f(ub & 0xffffu);
      float hi = bf2f(ua >> 16)     + bf2f(ub >> 16);
      lo += (w < 2) ? b0[w * 2]     : b1v[(w - 2) * 2];
      hi += (w < 2) ? b0[w * 2 + 1] : b1v[(w - 2) * 2 + 1];
      p[w] = f2bf(lo) | ((unsigned int)f2bf(hi) << 16);
    }
    *(i32x4*)&Cs[r * 136 + ch * 8] = *(i32x4*)p;
  }
  __syncthreads();
  // Phase 2 (merged 2+3): read tsum from Cs, add acc, relu, store DIRECT.
  // 16-lane groups store 32B contiguous; 4 ni-segments of one row share a
  // 128B line -> L2 write-combines. C/D layout: col=lane&15, row=quad*4+reg.
#pragma unroll
  for (int mi = 0; mi < 4; mi++) {
#pragma unroll
    for (int reg = 0; reg < 4; reg++) {
      int rloc = wm * 64 + mi * 16 + quad * 4 + reg;
      long row = rowbase + rloc;
#pragma unroll
      for (int ni = 0; ni < 4; ni++) {
        int cloc = wn * 64 + ni * 16 + r16;
        float v = acc[mi][ni][reg] + bf2f(Cs[rloc * 136 + cloc]);
        h1out[row * 1024 + colbase + cloc] = f2bf(fmaxf(v, 0.f));
      }
    }
  }
}

// ---------------------------------------------------------------- GEMM2 (fused)

// scores += relu(h1(65536x1024,bf16) @ W2 + b2) @ W3.  BK=64, XOR-swizzled
// LDS, single-buffered, 16 K-iterations — the R6 winner (~1012 TF), frozen.
__launch_bounds__(256, 2)
__global__ void gemm2_kernel(const unsigned short* __restrict__ A,
                             const unsigned short* __restrict__ BT,
                             const float* __restrict__ bias,
                             const float* __restrict__ w3,
                             float* __restrict__ scores) {
  __shared__ unsigned short As[128 * 64];  // [row][k] 16KB
  __shared__ unsigned short Bs[128 * 64];  // [n][k]   16KB

  const int tid  = threadIdx.x;
  const int lane = tid & 63;
  const int wave = tid >> 6;
  const int wm   = wave & 1;
  const int wn   = wave >> 1;
  const int quad = lane >> 4;
  const int r16  = lane & 15;

  const int bx    = blockIdx.x;
  const int xcd   = bx & 7;
  const int seq   = bx >> 3;
  const int ntile = seq & 7;
  const int mtile = ((seq >> 3) << 3) | xcd;
  const long rowbase = (long)mtile * 128;
  const int  colbase = ntile * 128;

  const f32x4 zero4 = {0.f, 0.f, 0.f, 0.f};
  f32x4 acc[4][4];
#pragma unroll
  for (int i = 0; i < 4; i++)
#pragma unroll
    for (int j = 0; j < 4; j++) acc[i][j] = zero4;

  // epilogue constants hoisted (8 scalar loads, L2-resident)
  float bias_r[4], w3_r[4];
#pragma unroll
  for (int ni = 0; ni < 4; ni++) {
    int col = colbase + wn * 64 + ni * 16 + r16;
    bias_r[ni] = bias[col];
    w3_r[ni]   = w3[col];
  }

  // staging: 1024 chunks/matrix; thread owns 4 A-chunks + 4 B-chunks per iter.
  int srow[4], skc[4];
#pragma unroll
  for (int i = 0; i < 4; i++) {
    int c = i * 256 + tid;
    srow[i] = c >> 3;
    skc[i]  = (c & 7) ^ (srow[i] & 7);
  }

  for (int k0 = 0; k0 < 1024; k0 += 64) {
#pragma unroll
    for (int i = 0; i < 4; i++) {
      int c = i * 256 + tid;
      async_copy16(A + (rowbase + srow[i]) * 1024 + k0 + skc[i] * 8, &As[c * 8]);
    }
#pragma unroll
    for (int i = 0; i < 4; i++) {
      int c = i * 256 + tid;
      async_copy16(BT + (long)(colbase + srow[i]) * 1024 + k0 + skc[i] * 8, &Bs[c * 8]);
    }
    __syncthreads();

#pragma unroll
    for (int ks = 0; ks < 2; ks++) {
      bf16x8 af[4], bfv[4];
#pragma unroll
      for (int mi = 0; mi < 4; mi++) {
        int r = wm * 64 + mi * 16 + r16;
        int phys = (ks * 4 + quad) ^ (r16 & 7);
        af[mi] = *(const bf16x8*)&As[r * 64 + phys * 8];
      }
#pragma unroll
      for (int ni = 0; ni < 4; ni++) {
        int r = wn * 64 + ni * 16 + r16;
        int phys = (ks * 4 + quad) ^ (r16 & 7);
        bfv[ni] = *(const bf16x8*)&Bs[r * 64 + phys * 8];
      }
#pragma unroll
      for (int mi = 0; mi < 4; mi++)
#pragma unroll
        for (int ni = 0; ni < 4; ni++)
          acc[mi][ni] = __builtin_amdgcn_mfma_f32_16x16x32_bf16(af[mi], bfv[ni],
                                                                acc[mi][ni], 0, 0, 0);
    }
    __syncthreads();
  }

  // epilogue: relu(x + b2) dot w3, shfl-reduce over 16 cols, one atomic per row.
#pragma unroll
  for (int mi = 0; mi < 4; mi++) {
#pragma unroll
    for (int reg = 0; reg < 4; reg++) {
      long row = rowbase + wm * 64 + mi * 16 + quad * 4 + reg;
      float part = 0.f;
#pragma unroll
      for (int ni = 0; ni < 4; ni++) {
        float v = fmaxf(acc[mi][ni][reg] + bias_r[ni], 0.f);
        part += v * w3_r[ni];
      }
      part += __shfl_xor(part, 1, 16);
      part += __shfl_xor(part, 2, 16);
      part += __shfl_xor(part, 4, 16);
      part += __shfl_xor(part, 8, 16);
      if (r16 == 0) atomicAdd(&scores[row], part);
    }
  }
}

// ---------------------------------------------------------------- launch

extern "C" void kernel_launch(void* const* d_in, const int* in_sizes, int n_in,
                              void* d_out, int out_size, void* d_ws, size_t ws_size,
                              hipStream_t stream) {
  const float* pfm  = (const float*)d_in[0];  // (256,19,19)
  const float* cand = (const float*)d_in[1];  // (65536,64)
  const float* W1   = (const float*)d_in[2];  // (832,1024)
  const float* b1   = (const float*)d_in[3];  // (1024,)
  const float* W2   = (const float*)d_in[4];  // (1024,1024)
  const float* b2   = (const float*)d_in[5];  // (1024,)
  const float* W3   = (const float*)d_in[6];  // (1024,1)
  const float* b3   = (const float*)d_in[7];  // (1,)
  float* scores = (float*)d_out;              // (65536,)

  char* ws = (char*)d_ws;
  float*          gp      = (float*)(ws + 0);                // 1 KB
  float*          b1p     = (float*)(ws + 1024);             // 4 KB
  unsigned short* Tb      = (unsigned short*)(ws + 8192);    // 1,478,656
  int*            go_off  = (int*)(ws + 1486848);            // 256 KB
  int*            to_off  = (int*)(ws + 1748992);            // 256 KB
  unsigned short* w1cT    = (unsigned short*)(ws + 2011136); // 128 KB
  unsigned short* w2T     = (unsigned short*)(ws + 2142208); // 2 MB
  unsigned short* h1      = (unsigned short*)(ws + 4239360); // 128 MB
  // total ws need: 138,457,088 bytes
  if (ws_size < 138457088) return;  // loud correctness failure instead of corruption

  pool_kernel<<<64, 256, 0, stream>>>(pfm, gp, b1, b1p);
  prep_kernel<<<1520, 256, 0, stream>>>(pfm, cand, W1, gp, W2, b3,
                                        go_off, to_off, scores, w1cT, w2T, Tb, b1p);
  // h1 = relu(cand@W1c + T_go[g] + T_to[t] + b1')   M=65536,K=64
  gemm1_kernel<<<4096, 256, 0, stream>>>(cand, w1cT, h1, Tb, go_off, to_off, b1p);
  // scores += relu(h1@W2 + b2) @ w3                 M=65536,K=1024
  gemm2_kernel<<<4096, 256, 0, stream>>>(h1, w2T, b2, W3, scores);
}

// Round 11
// 274.582 us; speedup vs baseline: 1.0634x; 1.0634x over previous
//
#include <hip/hip_runtime.h>

// CandidateScorer on MI355X (gfx950).
//
// Math (exact rewrite of the reference):
//   gp-part of combined is candidate-independent      -> folded into bias b1'
//   go/to gathers take only 361 distinct values each  -> precomputed tables
//   h1[n,j] = relu(T_go[go[n],j] + T_to[to[n],j] + (cand @ W1c)[n,j] + b1'[j])
//   scores  = relu(h1 @ W2 + b2) @ W3 + b3   (GEMM3 fused into GEMM2 epilogue)
//
// R1: XCD swizzle (FETCH 529->93 MB). R3: BK=64 + XOR LDS swizzle
//     (conflicts 1.7e7->0, ~1012 TF = 41% dense). R4: Ttab bf16.
// R5: parallel pool fix. R6: best measured total (281.2 us).
// R7 (dbuf@64KB: occupancy cliff), R8 (dbuf@32KB: 64B rows alias 16/32
// banks), R9 (ttab unroll), R10 (direct epilogue stores) ALL regressed.
// R11: exact revert to R6 — the empirically dominant configuration.
// Remaining gap is structural: gemm2 needs hand-asm-style K-loop
// restructuring (hipBLASLt-class) to pass 41% dense; gemm1 is
// latency/L2-bound; ~40 us is harness restore + launch gaps.

using bf16x8 = __attribute__((ext_vector_type(8))) __bf16;
using f32x4  = __attribute__((ext_vector_type(4))) float;
using i32x4  = __attribute__((ext_vector_type(4))) int;

__device__ __forceinline__ unsigned short f2bf(float f) {
  unsigned int u = __float_as_uint(f);
  u += 0x7fffu + ((u >> 16) & 1u);          // round-to-nearest-even
  return (unsigned short)(u >> 16);
}
__device__ __forceinline__ float bf2f(unsigned int s) {
  return __uint_as_float(s << 16);
}

// Async global->LDS, 16B per lane. LDS dest is wave-uniform base + lane*16.
__device__ __forceinline__ void async_copy16(const void* g, void* l) {
  __builtin_amdgcn_global_load_lds(
      (__attribute__((address_space(1))) void*)(unsigned long long)g,
      (__attribute__((address_space(3))) void*)(unsigned int)(unsigned long long)l,
      16, 0, 0);
}

// ---------------------------------------------------------------- pool
// 64 blocks x 256 threads: wave w reduces channel bx*4+w (fully parallel).
// Blocks 0-3 additionally init b1p = b1 (atomic target for prep's b1p range).
__global__ void pool_kernel(const float* __restrict__ pfm, float* __restrict__ gp,
                            const float* __restrict__ b1, float* __restrict__ b1p) {
  int t = threadIdx.x, bx = blockIdx.x;
  int wave = t >> 6, lane = t & 63;
  int c = bx * 4 + wave;
  float s = 0.f;
  for (int i = lane; i < 361; i += 64) s += pfm[c * 361 + i];
#pragma unroll
  for (int off = 32; off > 0; off >>= 1) s += __shfl_down(s, off, 64);
  if (lane == 0) gp[c] = s * (1.0f / 361.0f);
  if (bx < 4) b1p[bx * 256 + t] = b1[bx * 256 + t];
}

// ---------------------------------------------------------------- fused prep
// Block ranges (long pole first):
//   [0,368)      Ttab (bf16): T[s][pos][j] = sum_c pfm[c][pos]*W1[s*256+c][j]
//   [368,496)    b1p[j] += sum over 8 channels of gp[c]*W1[512+c][j] (atomic)
//   [496,752)    w2T[n][k] = bf16(W2[k][n])  (64x64 LDS-tiled transpose)
//   [752,1008)   go/to decode
//   [1008,1264)  scores = b3
//   [1264,1520)  w1cT[n][k] = bf16(W1[768+k][n])
__global__ void prep_kernel(const float* __restrict__ pfm, const float* __restrict__ cand,
                            const float* __restrict__ W1, const float* __restrict__ gp,
                            const float* __restrict__ W2, const float* __restrict__ b3,
                            int* __restrict__ go_off, int* __restrict__ to_off,
                            float* __restrict__ scores,
                            unsigned short* __restrict__ w1cT,
                            unsigned short* __restrict__ w2T,
                            unsigned short* __restrict__ Tb,
                            float* __restrict__ b1p) {
  __shared__ __align__(16) char smem[16640];
  int bx = blockIdx.x, t = threadIdx.x;

  if (bx < 368) {
    int b = bx;                      // 2 * 46 * 4 = 368 blocks
    int s = b / 184;
    int rem = b % 184;
    int p8 = rem >> 2;
    int jc = rem & 3;
    int j = jc * 256 + t;
    float (*pf)[256] = (float(*)[256])smem;   // [8][256] = 8KB
#pragma unroll
    for (int i = 0; i < 8; i++) {
      int p = p8 * 8 + i;
      pf[i][t] = (p < 361) ? pfm[t * 361 + p] : 0.f;   // t = channel
    }
    __syncthreads();
    float acc[8] = {0.f, 0.f, 0.f, 0.f, 0.f, 0.f, 0.f, 0.f};
    for (int c = 0; c < 256; c++) {
      float w = W1[(size_t)(s * 256 + c) * 1024 + j];
#pragma unroll
      for (int i = 0; i < 8; i++) acc[i] += pf[i][c] * w;
    }
#pragma unroll
    for (int i = 0; i < 8; i++) {
      int p = p8 * 8 + i;
      if (p < 361) Tb[((size_t)s * 361 + p) * 1024 + j] = f2bf(acc[i]);
    }
  } else if (bx < 496) {
    int b = bx - 368;                // 128 blocks: (jc 0..3) x (cchunk 0..31)
    int j = (b & 3) * 256 + t;
    int c0 = (b >> 2) * 8;
    float acc = 0.f;
#pragma unroll
    for (int i = 0; i < 8; i++)
      acc += gp[c0 + i] * W1[(size_t)(512 + c0 + i) * 1024 + j];
    atomicAdd(&b1p[j], acc);
  } else if (bx < 752) {
    int b = bx - 496;                // 256 tiles (16 x 16)
    float (*Ts)[65] = (float(*)[65])smem;     // [64][65] = 16640 B
    int kt = b >> 4, nt = b & 15;
#pragma unroll
    for (int i = 0; i < 4; i++) {
      int c = i * 256 + t;           // 1024 f32x4 chunks
      int r = c >> 4, ch = c & 15;
      f32x4 v = *(const f32x4*)&W2[(size_t)(kt * 64 + r) * 1024 + nt * 64 + ch * 4];
      Ts[r][ch * 4 + 0] = v[0]; Ts[r][ch * 4 + 1] = v[1];
      Ts[r][ch * 4 + 2] = v[2]; Ts[r][ch * 4 + 3] = v[3];
    }
    __syncthreads();
#pragma unroll
    for (int i = 0; i < 2; i++) {
      int c = i * 256 + t;           // 512 out-chunks of 8 bf16
      int n = c >> 3, ch = c & 7;
      unsigned short pack[8];
#pragma unroll
      for (int j = 0; j < 8; j++) pack[j] = f2bf(Ts[ch * 8 + j][n]);
      *(i32x4*)&w2T[(size_t)(nt * 64 + n) * 1024 + kt * 64 + ch * 8] = *(i32x4*)pack;
    }
  } else if (bx < 1008) {
    int n = (bx - 752) * 256 + t;
    const float* cf = cand + (size_t)n * 64;
    int gr = min(max((int)(cf[5] * 18.0f), 0), 18);
    int gc = min(max((int)(cf[6] * 18.0f), 0), 18);
    int tr = min(max((int)(cf[7] * 18.0f), 0), 18);
    int tc = min(max((int)(cf[8] * 18.0f), 0), 18);
    go_off[n] = gr * 19 + gc;
    to_off[n] = tr * 19 + tc;
  } else if (bx < 1264) {
    scores[(bx - 1008) * 256 + t] = b3[0];
  } else {
    int o = (bx - 1264) * 256 + t;   // < 65536
    int n = o >> 6, k = o & 63;
    w1cT[o] = f2bf(W1[(size_t)(768 + k) * 1024 + n]);
  }
}

// ---------------------------------------------------------------- GEMM1 (fused)

// h1(65536 x 1024) = relu(cand(f32) @ W1c + T_go[go] + T_to[to] + b1p)
// 128x128 tile, K=64 single step. A staged via f32 load + convert + ds_write;
// B via async_copy16. LDS XOR-swizzled (chunk (row,s) holds kchunk s^(row&7)).
__launch_bounds__(256, 2)
__global__ void gemm1_kernel(const float* __restrict__ cand,
                             const unsigned short* __restrict__ w1cT,
                             unsigned short* __restrict__ h1out,
                             const unsigned short* __restrict__ Tb,
                             const int* __restrict__ go_off,
                             const int* __restrict__ to_off,
                             const float* __restrict__ bias) {
  __shared__ __align__(16) char smem[34816];           // max(32K stage, 34K Cs)
  unsigned short* As = (unsigned short*)smem;          // [128][64] 16KB
  unsigned short* Bs = (unsigned short*)(smem + 16384);// [128][64] 16KB
  unsigned short* Cs = (unsigned short*)smem;          // [128][136] bf16 (aliased)

  const int tid  = threadIdx.x;
  const int lane = tid & 63;
  const int wave = tid >> 6;
  const int wm   = wave & 1;
  const int wn   = wave >> 1;
  const int quad = lane >> 4;
  const int r16  = lane & 15;

  const int bx    = blockIdx.x;
  const int xcd   = bx & 7;
  const int seq   = bx >> 3;
  const int ntile = seq & 7;
  const int mtile = ((seq >> 3) << 3) | xcd;
  const long rowbase = (long)mtile * 128;
  const int  colbase = ntile * 128;

  // ---- stage A: load f32, convert, ds_write (4 chunks of 16B per thread)
#pragma unroll
  for (int i = 0; i < 4; i++) {
    int c = i * 256 + tid;                 // physical chunk
    int row = c >> 3, s = c & 7;
    int kc = s ^ (row & 7);                // logical k-chunk
    const float* src = cand + (rowbase + row) * 64 + kc * 8;
    f32x4 v0 = *(const f32x4*)src;
    f32x4 v1 = *(const f32x4*)(src + 4);
    unsigned int p[4];
    p[0] = f2bf(v0[0]) | ((unsigned int)f2bf(v0[1]) << 16);
    p[1] = f2bf(v0[2]) | ((unsigned int)f2bf(v0[3]) << 16);
    p[2] = f2bf(v1[0]) | ((unsigned int)f2bf(v1[1]) << 16);
    p[3] = f2bf(v1[2]) | ((unsigned int)f2bf(v1[3]) << 16);
    *(i32x4*)&As[c * 8] = *(i32x4*)p;
  }
  // ---- stage B: async copy w1cT tile (4 chunks per thread)
#pragma unroll
  for (int i = 0; i < 4; i++) {
    int c = i * 256 + tid;
    int row = c >> 3, s = c & 7;
    int kc = s ^ (row & 7);
    async_copy16(w1cT + (colbase + row) * 64 + kc * 8, &Bs[c * 8]);
  }
  __syncthreads();

  const f32x4 zero4 = {0.f, 0.f, 0.f, 0.f};
  f32x4 acc[4][4];
#pragma unroll
  for (int i = 0; i < 4; i++)
#pragma unroll
    for (int j = 0; j < 4; j++) acc[i][j] = zero4;

#pragma unroll
  for (int ks = 0; ks < 2; ks++) {
    bf16x8 af[4], bfv[4];
#pragma unroll
    for (int mi = 0; mi < 4; mi++) {
      int r = wm * 64 + mi * 16 + r16;
      int phys = (ks * 4 + quad) ^ (r16 & 7);
      af[mi] = *(const bf16x8*)&As[r * 64 + phys * 8];
    }
#pragma unroll
    for (int ni = 0; ni < 4; ni++) {
      int r = wn * 64 + ni * 16 + r16;
      int phys = (ks * 4 + quad) ^ (r16 & 7);
      bfv[ni] = *(const bf16x8*)&Bs[r * 64 + phys * 8];
    }
#pragma unroll
    for (int mi = 0; mi < 4; mi++)
#pragma unroll
      for (int ni = 0; ni < 4; ni++)
        acc[mi][ni] = __builtin_amdgcn_mfma_f32_16x16x32_bf16(af[mi], bfv[ni],
                                                              acc[mi][ni], 0, 0, 0);
  }
  __syncthreads();   // staging LDS dead; Cs takes over

  // Phase 1: Cs[r][c] = bf16(T_go[go[r]][c] + T_to[to[r]][c] + bias[c]).
  // bf16 tables: one i32x4 (8 bf16) per gather — half the bytes of f32.
#pragma unroll
  for (int i = 0; i < 8; i++) {
    int c = i * 256 + tid;                    // 2048 chunks of 8 cols
    int r = c >> 4, ch = c & 15;
    long grow = rowbase + r;
    const unsigned short* tg = Tb + (long)go_off[grow] * 1024 + colbase + ch * 8;
    const unsigned short* tt = Tb + 361L * 1024 + (long)to_off[grow] * 1024 + colbase + ch * 8;
    i32x4 ga = *(const i32x4*)tg;
    i32x4 gb = *(const i32x4*)tt;
    const float* bp = bias + colbase + ch * 8;
    f32x4 b0 = *(const f32x4*)bp;
    f32x4 b1v = *(const f32x4*)(bp + 4);
    unsigned int p[4];
#pragma unroll
    for (int w = 0; w < 4; w++) {
      unsigned int ua = (unsigned int)ga[w], ub = (unsigned int)gb[w];
      float lo = bf2f(ua & 0xffffu) + bf2f(ub & 0xffffu);
      float hi = bf2f(ua >> 16)     + bf2f(ub >> 16);
      lo += (w < 2) ? b0[w * 2]     : b1v[(w - 2) * 2];
      hi += (w < 2) ? b0[w * 2 + 1] : b1v[(w - 2) * 2 + 1];
      p[w] = f2bf(lo) | ((unsigned int)f2bf(hi) << 16);
    }
    *(i32x4*)&Cs[r * 136 + ch * 8] = *(i32x4*)p;
  }
  __syncthreads();
  // Phase 2: in-place RMW — each (rloc,cloc) touched by exactly one thread.
  // C/D layout: col = lane&15, row = quad*4 + reg  (m89/m91-verified)
#pragma unroll
  for (int mi = 0; mi < 4; mi++) {
#pragma unroll
    for (int reg = 0; reg < 4; reg++) {
      int rloc = wm * 64 + mi * 16 + quad * 4 + reg;
#pragma unroll
      for (int ni = 0; ni < 4; ni++) {
        int cloc = wn * 64 + ni * 16 + r16;
        float v = acc[mi][ni][reg] + bf2f(Cs[rloc * 136 + cloc]);
        Cs[rloc * 136 + cloc] = f2bf(fmaxf(v, 0.f));
      }
    }
  }
  __syncthreads();
  // Phase 3: 16B-coalesced global stores.
#pragma unroll
  for (int i = 0; i < 8; i++) {
    int c = i * 256 + tid;
    int r = c >> 4, cc = c & 15;
    *(i32x4*)(h1out + (rowbase + r) * 1024 + colbase + cc * 8) =
        *(const i32x4*)&Cs[r * 136 + cc * 8];
  }
}

// ---------------------------------------------------------------- GEMM2 (fused)

// scores += relu(h1(65536x1024,bf16) @ W2 + b2) @ W3.  BK=64, XOR-swizzled
// LDS, single-buffered, 16 K-iterations — the R6 winner (~1012 TF), frozen.
__launch_bounds__(256, 2)
__global__ void gemm2_kernel(const unsigned short* __restrict__ A,
                             const unsigned short* __restrict__ BT,
                             const float* __restrict__ bias,
                             const float* __restrict__ w3,
                             float* __restrict__ scores) {
  __shared__ unsigned short As[128 * 64];  // [row][k] 16KB
  __shared__ unsigned short Bs[128 * 64];  // [n][k]   16KB

  const int tid  = threadIdx.x;
  const int lane = tid & 63;
  const int wave = tid >> 6;
  const int wm   = wave & 1;
  const int wn   = wave >> 1;
  const int quad = lane >> 4;
  const int r16  = lane & 15;

  const int bx    = blockIdx.x;
  const int xcd   = bx & 7;
  const int seq   = bx >> 3;
  const int ntile = seq & 7;
  const int mtile = ((seq >> 3) << 3) | xcd;
  const long rowbase = (long)mtile * 128;
  const int  colbase = ntile * 128;

  const f32x4 zero4 = {0.f, 0.f, 0.f, 0.f};
  f32x4 acc[4][4];
#pragma unroll
  for (int i = 0; i < 4; i++)
#pragma unroll
    for (int j = 0; j < 4; j++) acc[i][j] = zero4;

  // epilogue constants hoisted (8 scalar loads, L2-resident)
  float bias_r[4], w3_r[4];
#pragma unroll
  for (int ni = 0; ni < 4; ni++) {
    int col = colbase + wn * 64 + ni * 16 + r16;
    bias_r[ni] = bias[col];
    w3_r[ni]   = w3[col];
  }

  // staging: 1024 chunks/matrix; thread owns 4 A-chunks + 4 B-chunks per iter.
  int srow[4], skc[4];
#pragma unroll
  for (int i = 0; i < 4; i++) {
    int c = i * 256 + tid;
    srow[i] = c >> 3;
    skc[i]  = (c & 7) ^ (srow[i] & 7);
  }

  for (int k0 = 0; k0 < 1024; k0 += 64) {
#pragma unroll
    for (int i = 0; i < 4; i++) {
      int c = i * 256 + tid;
      async_copy16(A + (rowbase + srow[i]) * 1024 + k0 + skc[i] * 8, &As[c * 8]);
    }
#pragma unroll
    for (int i = 0; i < 4; i++) {
      int c = i * 256 + tid;
      async_copy16(BT + (long)(colbase + srow[i]) * 1024 + k0 + skc[i] * 8, &Bs[c * 8]);
    }
    __syncthreads();

#pragma unroll
    for (int ks = 0; ks < 2; ks++) {
      bf16x8 af[4], bfv[4];
#pragma unroll
      for (int mi = 0; mi < 4; mi++) {
        int r = wm * 64 + mi * 16 + r16;
        int phys = (ks * 4 + quad) ^ (r16 & 7);
        af[mi] = *(const bf16x8*)&As[r * 64 + phys * 8];
      }
#pragma unroll
      for (int ni = 0; ni < 4; ni++) {
        int r = wn * 64 + ni * 16 + r16;
        int phys = (ks * 4 + quad) ^ (r16 & 7);
        bfv[ni] = *(const bf16x8*)&Bs[r * 64 + phys * 8];
      }
#pragma unroll
      for (int mi = 0; mi < 4; mi++)
#pragma unroll
        for (int ni = 0; ni < 4; ni++)
          acc[mi][ni] = __builtin_amdgcn_mfma_f32_16x16x32_bf16(af[mi], bfv[ni],
                                                                acc[mi][ni], 0, 0, 0);
    }
    __syncthreads();
  }

  // epilogue: relu(x + b2) dot w3, shfl-reduce over 16 cols, one atomic per row.
#pragma unroll
  for (int mi = 0; mi < 4; mi++) {
#pragma unroll
    for (int reg = 0; reg < 4; reg++) {
      long row = rowbase + wm * 64 + mi * 16 + quad * 4 + reg;
      float part = 0.f;
#pragma unroll
      for (int ni = 0; ni < 4; ni++) {
        float v = fmaxf(acc[mi][ni][reg] + bias_r[ni], 0.f);
        part += v * w3_r[ni];
      }
      part += __shfl_xor(part, 1, 16);
      part += __shfl_xor(part, 2, 16);
      part += __shfl_xor(part, 4, 16);
      part += __shfl_xor(part, 8, 16);
      if (r16 == 0) atomicAdd(&scores[row], part);
    }
  }
}

// ---------------------------------------------------------------- launch

extern "C" void kernel_launch(void* const* d_in, const int* in_sizes, int n_in,
                              void* d_out, int out_size, void* d_ws, size_t ws_size,
                              hipStream_t stream) {
  const float* pfm  = (const float*)d_in[0];  // (256,19,19)
  const float* cand = (const float*)d_in[1];  // (65536,64)
  const float* W1   = (const float*)d_in[2];  // (832,1024)
  const float* b1   = (const float*)d_in[3];  // (1024,)
  const float* W2   = (const float*)d_in[4];  // (1024,1024)
  const float* b2   = (const float*)d_in[5];  // (1024,)
  const float* W3   = (const float*)d_in[6];  // (1024,1)
  const float* b3   = (const float*)d_in[7];  // (1,)
  float* scores = (float*)d_out;              // (65536,)

  char* ws = (char*)d_ws;
  float*          gp      = (float*)(ws + 0);                // 1 KB
  float*          b1p     = (float*)(ws + 1024);             // 4 KB
  unsigned short* Tb      = (unsigned short*)(ws + 8192);    // 1,478,656
  int*            go_off  = (int*)(ws + 1486848);            // 256 KB
  int*            to_off  = (int*)(ws + 1748992);            // 256 KB
  unsigned short* w1cT    = (unsigned short*)(ws + 2011136); // 128 KB
  unsigned short* w2T     = (unsigned short*)(ws + 2142208); // 2 MB
  unsigned short* h1      = (unsigned short*)(ws + 4239360); // 128 MB
  // total ws need: 138,457,088 bytes
  if (ws_size < 138457088) return;  // loud correctness failure instead of corruption

  pool_kernel<<<64, 256, 0, stream>>>(pfm, gp, b1, b1p);
  prep_kernel<<<1520, 256, 0, stream>>>(pfm, cand, W1, gp, W2, b3,
                                        go_off, to_off, scores, w1cT, w2T, Tb, b1p);
  // h1 = relu(cand@W1c + T_go[g] + T_to[t] + b1')   M=65536,K=64
  gemm1_kernel<<<4096, 256, 0, stream>>>(cand, w1cT, h1, Tb, go_off, to_off, b1p);
  // scores += relu(h1@W2 + b2) @ w3                 M=65536,K=1024
  gemm2_kernel<<<4096, 256, 0, stream>>>(h1, w2T, b2, W3, scores);
}